// Round 3
// baseline (581.510 us; speedup 1.0000x reference)
//
#include <hip/hip_runtime.h>
#include <stdint.h>

#define DIM 16
#define HID 128
#define TN  32
#define ROWF 132          // LDS row stride in floats (128 + 4 pad)
#define EPSF 1e-5f

// NaN-free tanh; |x| <= ~12 here (LN output bounded by sqrt(H))
__device__ __forceinline__ float safe_tanh(float x) {
    float a = fabsf(x);
    float e = __expf(2.0f * a);
    float t = 1.0f - 2.0f / (e + 1.0f);
    return copysignf(t, x);
}

// ---------------- Phase 1: edge scatter-add -------------------------------
// 16 threads per edge (one per feature component).
__global__ void __launch_bounds__(256) edge_scatter_kernel(
    const float* __restrict__ nodes, const int* __restrict__ edges,
    const float* __restrict__ ew, float* __restrict__ agg_in,
    float* __restrict__ agg_out, int nEdges)
{
    int gid = blockIdx.x * 256 + threadIdx.x;
    int e = gid >> 4;
    if (e >= nEdges) return;
    int c = gid & 15;
    int src = edges[2 * e];
    int dst = edges[2 * e + 1];
    float w  = ew[e];
    float vs = nodes[src * DIM + c];
    float vd = nodes[dst * DIM + c];
    atomicAdd(&agg_in[dst * DIM + c], vs * w);   // agg_in[dst] += nodes[src]*w
    atomicAdd(&agg_out[src * DIM + c], vd * w);  // agg_out[src] += nodes[dst]*w
}

// ---------------- Phase 2: fused 4-layer MLP ------------------------------
// Block: 256 threads, 32-node tile. Thread owns 4 nodes x 4 cols.
template<int K>
__device__ __forceinline__ void dense_ln_tanh(
    const float* __restrict__ W, const float* __restrict__ bias,
    const float* __restrict__ g, const float* __restrict__ be,
    float (&X)[TN][ROWF], float* mean_s, float* rstd_s, int tid)
{
    const int c0 = (tid & 31) * 4;   // column group
    const int n0 = (tid >> 5) * 4;   // node group
    float acc[4][4];
    {
        float4 bv = *(const float4*)(bias + c0);
        #pragma unroll
        for (int i = 0; i < 4; ++i) {
            acc[i][0] = bv.x; acc[i][1] = bv.y; acc[i][2] = bv.z; acc[i][3] = bv.w;
        }
    }

    #pragma unroll 2
    for (int k = 0; k < K; k += 4) {
        float xr[4][4];
        #pragma unroll
        for (int i = 0; i < 4; ++i) {
            float4 t = *(const float4*)&X[n0 + i][k];
            xr[i][0] = t.x; xr[i][1] = t.y; xr[i][2] = t.z; xr[i][3] = t.w;
        }
        float w[4][4];
        #pragma unroll
        for (int kk = 0; kk < 4; ++kk) {
            float4 t = *(const float4*)(W + (k + kk) * HID + c0);
            w[kk][0] = t.x; w[kk][1] = t.y; w[kk][2] = t.z; w[kk][3] = t.w;
        }
        #pragma unroll
        for (int kk = 0; kk < 4; ++kk)
            #pragma unroll
            for (int i = 0; i < 4; ++i)
                #pragma unroll
                for (int j = 0; j < 4; ++j) acc[i][j] += xr[i][kk] * w[kk][j];
    }
    __syncthreads();   // all reads of X done before overwrite
    #pragma unroll
    for (int i = 0; i < 4; ++i)
        *(float4*)&X[n0 + i][c0] = make_float4(acc[i][0], acc[i][1], acc[i][2], acc[i][3]);
    __syncthreads();

    // LayerNorm stats: 8 threads per node over 128 cols
    {
        const int n = tid >> 3;
        const int s = tid & 7;
        float sum = 0.f, sq = 0.f;
        #pragma unroll
        for (int i = 0; i < 16; ++i) {
            float v = X[n][s * 16 + i];
            sum += v; sq += v * v;
        }
        #pragma unroll
        for (int m = 1; m <= 4; m <<= 1) {
            sum += __shfl_xor(sum, m);
            sq  += __shfl_xor(sq, m);
        }
        if (s == 0) {
            float mean = sum * (1.0f / HID);
            float var  = sq * (1.0f / HID) - mean * mean;
            mean_s[n] = mean;
            rstd_s[n] = rsqrtf(fmaxf(var, 0.0f) + EPSF);
        }
    }
    __syncthreads();

    {
        float4 gv  = *(const float4*)(g + c0);
        float4 bev = *(const float4*)(be + c0);
        float gr[4]  = {gv.x, gv.y, gv.z, gv.w};
        float ber[4] = {bev.x, bev.y, bev.z, bev.w};
        #pragma unroll
        for (int i = 0; i < 4; ++i) {
            float m = mean_s[n0 + i], r = rstd_s[n0 + i];
            #pragma unroll
            for (int j = 0; j < 4; ++j)
                acc[i][j] = safe_tanh((acc[i][j] - m) * r * gr[j] + ber[j]);
            *(float4*)&X[n0 + i][c0] = make_float4(acc[i][0], acc[i][1], acc[i][2], acc[i][3]);
        }
    }
    __syncthreads();
}

__global__ void __launch_bounds__(256) mlp_kernel(
    const float* __restrict__ agg_in, const float* __restrict__ agg_out,
    const float* __restrict__ nodes,
    const float* __restrict__ W1, const float* __restrict__ b1, const float* __restrict__ g1, const float* __restrict__ be1,
    const float* __restrict__ W2, const float* __restrict__ b2, const float* __restrict__ g2, const float* __restrict__ be2,
    const float* __restrict__ W3, const float* __restrict__ b3, const float* __restrict__ g3, const float* __restrict__ be3,
    const float* __restrict__ W4, const float* __restrict__ b4, const float* __restrict__ g4, const float* __restrict__ be4,
    float* __restrict__ out, int nNodes)
{
    __shared__ float X[TN][ROWF];
    __shared__ float mean_s[TN], rstd_s[TN];

    const int tid = threadIdx.x;
    const int node0 = blockIdx.x * TN;
    if (node0 >= nNodes) return;

    // stage x = concat(agg_in, agg_out, nodes) : [32][48]
    for (int i = tid; i < TN * 48; i += 256) {
        int n = i / 48, c = i - n * 48;
        int gn = node0 + n;
        float v;
        if (c < 16)      v = agg_in[gn * DIM + c];
        else if (c < 32) v = agg_out[gn * DIM + (c - 16)];
        else             v = nodes[gn * DIM + (c - 32)];
        X[n][c] = v;
    }
    __syncthreads();

    dense_ln_tanh<48>(W1, b1, g1, be1, X, mean_s, rstd_s, tid);
    dense_ln_tanh<128>(W2, b2, g2, be2, X, mean_s, rstd_s, tid);
    dense_ln_tanh<128>(W3, b3, g3, be3, X, mean_s, rstd_s, tid);

    // Layer 4: 128 -> 16, LN over 16, tanh, store fp32
    {
        const int c2 = tid & 15;
        const int nn = tid >> 4;   // 0..15 ; handles nodes nn and nn+16
        float aA = b4[c2];
        float aB = aA;
        #pragma unroll 4
        for (int k = 0; k < HID; k += 4) {
            float4 xA = *(const float4*)&X[nn][k];
            float4 xB = *(const float4*)&X[nn + 16][k];
            float xa[4] = {xA.x, xA.y, xA.z, xA.w};
            float xb[4] = {xB.x, xB.y, xB.z, xB.w};
            #pragma unroll
            for (int kk = 0; kk < 4; ++kk) {
                float w = W4[(k + kk) * DIM + c2];
                aA += xa[kk] * w;
                aB += xb[kk] * w;
            }
        }
        float sA = aA, qA = aA * aA, sB = aB, qB = aB * aB;
        #pragma unroll
        for (int m = 1; m <= 8; m <<= 1) {
            sA += __shfl_xor(sA, m); qA += __shfl_xor(qA, m);
            sB += __shfl_xor(sB, m); qB += __shfl_xor(qB, m);
        }
        float g4v = g4[c2], be4v = be4[c2];
        float mA = sA * (1.0f / DIM), vA = fmaxf(qA * (1.0f / DIM) - mA * mA, 0.0f);
        float mB = sB * (1.0f / DIM), vB = fmaxf(qB * (1.0f / DIM) - mB * mB, 0.0f);
        float oA = safe_tanh((aA - mA) * rsqrtf(vA + EPSF) * g4v + be4v);
        float oB = safe_tanh((aB - mB) * rsqrtf(vB + EPSF) * g4v + be4v);
        out[(size_t)(node0 + nn) * DIM + c2]      = oA;
        out[(size_t)(node0 + nn + 16) * DIM + c2] = oB;
    }
}

extern "C" void kernel_launch(void* const* d_in, const int* in_sizes, int n_in,
                              void* d_out, int out_size, void* d_ws, size_t ws_size,
                              hipStream_t stream)
{
    const float* nodes = (const float*)d_in[0];
    const int*   edges = (const int*)d_in[1];
    const float* ew    = (const float*)d_in[2];
    const float *W1 = (const float*)d_in[3],  *b1 = (const float*)d_in[4],
                *g1 = (const float*)d_in[5],  *be1 = (const float*)d_in[6];
    const float *W2 = (const float*)d_in[7],  *b2 = (const float*)d_in[8],
                *g2 = (const float*)d_in[9],  *be2 = (const float*)d_in[10];
    const float *W3 = (const float*)d_in[11], *b3 = (const float*)d_in[12],
                *g3 = (const float*)d_in[13], *be3 = (const float*)d_in[14];
    const float *W4 = (const float*)d_in[15], *b4 = (const float*)d_in[16],
                *g4 = (const float*)d_in[17], *be4 = (const float*)d_in[18];

    const int nNodes = in_sizes[0] / DIM;   // 100000
    const int nEdges = in_sizes[2];         // 3200000

    float* agg_in  = (float*)d_ws;
    float* agg_out = agg_in + (size_t)nNodes * DIM;

    hipMemsetAsync(d_ws, 0, (size_t)2 * nNodes * DIM * sizeof(float), stream);

    long long ethreads = (long long)nEdges * 16;
    int egrid = (int)((ethreads + 255) / 256);
    edge_scatter_kernel<<<egrid, 256, 0, stream>>>(nodes, edges, ew, agg_in, agg_out, nEdges);

    int mgrid = (nNodes + TN - 1) / TN;
    mlp_kernel<<<mgrid, 256, 0, stream>>>(agg_in, agg_out, nodes,
        W1, b1, g1, be1, W2, b2, g2, be2, W3, b3, g3, be3, W4, b4, g4, be4,
        (float*)d_out, nNodes);
}